// Round 2
// baseline (507.330 us; speedup 1.0000x reference)
//
#include <hip/hip_runtime.h>
#include <cstdint>
#include <cstddef>

typedef unsigned short u16x8 __attribute__((ext_vector_type(8)));
typedef __bf16 bf16x8 __attribute__((ext_vector_type(8)));
typedef float f32x4 __attribute__((ext_vector_type(4)));

__device__ __forceinline__ float b2f(unsigned short u) {
    union { unsigned int i; float f; } v;
    v.i = ((unsigned int)u) << 16;
    return v.f;
}

__device__ __forceinline__ unsigned short f2b(float f) {
    union { float f; unsigned int i; } v;
    v.f = f;
    unsigned int x = v.i;
    unsigned int lsb = (x >> 16) & 1u;
    x += 0x7FFFu + lsb;           // round-to-nearest-even
    return (unsigned short)(x >> 16);
}

__device__ __forceinline__ float gelu_exact(float x) {
    return 0.5f * x * (1.0f + erff(x * 0.70710678118654752f));
}

// ---------------------------------------------------------------------------
// Transpose + cast: in is R x C row-major fp32, out is C x R row-major bf16.
// All dims used are multiples of 32.
// ---------------------------------------------------------------------------
__global__ void transpose_f32_bf16(const float* __restrict__ in,
                                   unsigned short* __restrict__ out, int R, int C) {
    __shared__ float tile[32][33];
    int x = blockIdx.x * 32 + threadIdx.x;
    int y0 = blockIdx.y * 32;
    for (int k = 0; k < 32; k += 8)
        tile[threadIdx.y + k][threadIdx.x] = in[(size_t)(y0 + threadIdx.y + k) * C + x];
    __syncthreads();
    int ox = y0 + threadIdx.x;        // col in out = original row
    int oy = blockIdx.x * 32;         // row block in out = original col
    for (int k = 0; k < 32; k += 8)
        out[(size_t)(oy + threadIdx.y + k) * R + ox] = f2b(tile[threadIdx.x][threadIdx.y + k]);
}

// ---------------------------------------------------------------------------
// Row LayerNorm over NPT*256 columns, block of 256 threads per row.
// TIN = float (reads fp32) or unsigned short (reads bf16). Output bf16.
// Safe in-place for bf16->bf16 (values buffered in registers first).
// ---------------------------------------------------------------------------
__device__ __forceinline__ float ldf(const float* p, int i) { return p[i]; }
__device__ __forceinline__ float ldf(const unsigned short* p, int i) { return b2f(p[i]); }

template <int NPT, typename TIN>
__global__ __launch_bounds__(256) void ln_rows(const TIN* __restrict__ in,
                                               unsigned short* __restrict__ out,
                                               const float* __restrict__ g,
                                               const float* __restrict__ b) {
    const int ncol = NPT * 256;
    const int row = blockIdx.x;
    const int t = threadIdx.x;
    const TIN* xr = in + (size_t)row * ncol;

    float v[NPT];
    float s = 0.f, s2 = 0.f;
#pragma unroll
    for (int i = 0; i < NPT; ++i) {
        float f = ldf(xr, t + (i << 8));
        v[i] = f;
        s += f;
        s2 += f * f;
    }
#pragma unroll
    for (int o = 32; o > 0; o >>= 1) {
        s  += __shfl_down(s, o, 64);
        s2 += __shfl_down(s2, o, 64);
    }
    __shared__ float red[8];
    int lane = t & 63, w = t >> 6;
    if (lane == 0) { red[w] = s; red[4 + w] = s2; }
    __syncthreads();
    if (t == 0) {
        red[0] = red[0] + red[1] + red[2] + red[3];
        red[4] = red[4] + red[5] + red[6] + red[7];
    }
    __syncthreads();
    float inv_n = 1.0f / (float)ncol;
    float mu = red[0] * inv_n;
    float var = red[4] * inv_n - mu * mu;
    float rs = rsqrtf(var + 1e-5f);

    unsigned short* orow = out + (size_t)row * ncol;
#pragma unroll
    for (int i = 0; i < NPT; ++i) {
        int c = t + (i << 8);
        orow[c] = f2b((v[i] - mu) * rs * g[c] + b[c]);
    }
}

// ---------------------------------------------------------------------------
// GEMM: epi(A[M x K] * BT[N x K]^T + bias). A,BT bf16; bias fp32; fp32 acc.
// Tile: BM=128, BN=128, BK=32; 256 threads = 4 waves, each wave 64x64.
// EPI: 0 = bias + exact GELU, store bf16 to Cb
//      1 = bias, store bf16 to Cb only where idx[row] == match
//      2 = bias, out fp32 Cf = val*wm[row] + adaptive_sel*(1-wm[row])
// ---------------------------------------------------------------------------
#define LDSS 40   // padded LDS row stride (80 B: 16B-aligned, bank-spread)

template <int EPI>
__global__ __launch_bounds__(256) void gemm_bt(
    const unsigned short* __restrict__ A, const unsigned short* __restrict__ BT,
    const float* __restrict__ bias, unsigned short* __restrict__ Cb,
    float* __restrict__ Cf, int M, int N, int K,
    const int* __restrict__ idx, int match,
    const float* __restrict__ wm,
    const unsigned short* __restrict__ adaptive,
    const unsigned short* __restrict__ xn) {
    __shared__ __align__(16) unsigned short As[128 * LDSS];
    __shared__ __align__(16) unsigned short Bs[128 * LDSS];

    const int t = threadIdx.x;
    const int m0 = blockIdx.y * 128;
    const int n0 = blockIdx.x * 128;

    const int r0 = t >> 2;              // 0..63
    const int kk = (t & 3) << 3;        // 0,8,16,24

    const int lane = t & 63;
    const int wid = t >> 6;
    const int wr = (wid >> 1) << 6;     // wave row offset: 0 or 64
    const int wc = (wid & 1) << 6;      // wave col offset: 0 or 64
    const int ml = lane & 15;
    const int q = lane >> 4;            // 0..3

    f32x4 acc[4][4];
#pragma unroll
    for (int i = 0; i < 4; ++i)
#pragma unroll
        for (int j = 0; j < 4; ++j)
#pragma unroll
            for (int r = 0; r < 4; ++r) acc[i][j][r] = 0.0f;

    for (int k0 = 0; k0 < K; k0 += 32) {
#pragma unroll
        for (int hh = 0; hh < 2; ++hh) {
            int row = r0 + (hh << 6);
            *(u16x8*)(&As[row * LDSS + kk]) =
                *(const u16x8*)(A + (size_t)(m0 + row) * K + k0 + kk);
            *(u16x8*)(&Bs[row * LDSS + kk]) =
                *(const u16x8*)(BT + (size_t)(n0 + row) * K + k0 + kk);
        }
        __syncthreads();

        bf16x8 af[4], bf[4];
#pragma unroll
        for (int i = 0; i < 4; ++i)
            af[i] = *(const bf16x8*)(&As[(wr + i * 16 + ml) * LDSS + (q << 3)]);
#pragma unroll
        for (int j = 0; j < 4; ++j)
            bf[j] = *(const bf16x8*)(&Bs[(wc + j * 16 + ml) * LDSS + (q << 3)]);
#pragma unroll
        for (int i = 0; i < 4; ++i)
#pragma unroll
            for (int j = 0; j < 4; ++j)
                acc[i][j] = __builtin_amdgcn_mfma_f32_16x16x32_bf16(af[i], bf[j], acc[i][j], 0, 0, 0);
        __syncthreads();
    }

    // C/D layout: col = lane&15, row = quad*4 + reg  [m89/m91-verified]
#pragma unroll
    for (int i = 0; i < 4; ++i) {
#pragma unroll
        for (int j = 0; j < 4; ++j) {
            int col = n0 + wc + j * 16 + ml;
            float bv = bias[col];
#pragma unroll
            for (int r = 0; r < 4; ++r) {
                int row = m0 + wr + i * 16 + q * 4 + r;
                float val = acc[i][j][r] + bv;
                size_t off = (size_t)row * N + col;
                if (EPI == 0) {
                    Cb[off] = f2b(gelu_exact(val));
                } else if (EPI == 1) {
                    if (idx[row] == match) Cb[off] = f2b(val);
                } else {
                    float w = wm[row];
                    int id = idx[row];
                    float a = b2f((id <= 1) ? adaptive[off] : xn[off]);
                    Cf[off] = val * w + a * (1.0f - w);
                }
            }
        }
    }
}

// ---------------------------------------------------------------------------
extern "C" void kernel_launch(void* const* d_in, const int* in_sizes, int n_in,
                              void* d_out, int out_size, void* d_ws, size_t ws_size,
                              hipStream_t stream) {
    const float* x       = (const float*)d_in[0];
    const float* wm      = (const float*)d_in[1];
    const int*   widx    = (const int*)d_in[2];
    const float* ln_in_g = (const float*)d_in[3];
    const float* ln_in_b = (const float*)d_in[4];
    const float* W1      = (const float*)d_in[5];
    const float* b1      = (const float*)d_in[6];
    const float* ln_h_g  = (const float*)d_in[7];
    const float* ln_h_b  = (const float*)d_in[8];
    const float* W2      = (const float*)d_in[9];
    const float* b2      = (const float*)d_in[10];
    const float* a256_w1 = (const float*)d_in[11];
    const float* a256_b1 = (const float*)d_in[12];
    const float* a256_w2 = (const float*)d_in[13];
    const float* a256_b2 = (const float*)d_in[14];
    const float* a512_w1 = (const float*)d_in[15];
    const float* a512_b1 = (const float*)d_in[16];
    const float* a512_w2 = (const float*)d_in[17];
    const float* a512_b2 = (const float*)d_in[18];
    float* out = (float*)d_out;

    const int T = 8192, H = 1024, F = 4096;

    unsigned short* ws0   = (unsigned short*)d_ws;
    unsigned short* xn    = ws0;                       // T*H      bf16
    unsigned short* h     = xn    + (size_t)T * H;     // T*F      bf16
    unsigned short* t0    = h     + (size_t)T * F;     // T*256    bf16
    unsigned short* t1    = t0    + (size_t)T * 256;   // T*512    bf16
    unsigned short* adp   = t1    + (size_t)T * 512;   // T*H      bf16
    unsigned short* W1T   = adp   + (size_t)T * H;     // F*H      bf16
    unsigned short* W2T   = W1T   + (size_t)H * F;     // H*F      bf16
    unsigned short* aw1T0 = W2T   + (size_t)F * H;     // 256*1024
    unsigned short* aw2T0 = aw1T0 + (size_t)256 * H;   // 1024*256
    unsigned short* aw1T1 = aw2T0 + (size_t)H * 256;   // 512*1024
    unsigned short* aw2T1 = aw1T1 + (size_t)512 * H;   // 1024*512

    dim3 tb(32, 8);
    transpose_f32_bf16<<<dim3(F / 32,   H / 32), tb, 0, stream>>>(W1,      W1T,   H,   F);
    transpose_f32_bf16<<<dim3(H / 32,   F / 32), tb, 0, stream>>>(W2,      W2T,   F,   H);
    transpose_f32_bf16<<<dim3(256 / 32, H / 32), tb, 0, stream>>>(a256_w1, aw1T0, H,   256);
    transpose_f32_bf16<<<dim3(H / 32, 256 / 32), tb, 0, stream>>>(a256_w2, aw2T0, 256, H);
    transpose_f32_bf16<<<dim3(512 / 32, H / 32), tb, 0, stream>>>(a512_w1, aw1T1, H,   512);
    transpose_f32_bf16<<<dim3(H / 32, 512 / 32), tb, 0, stream>>>(a512_w2, aw2T1, 512, H);

    // x (fp32) -> x_norm (bf16)
    ln_rows<4, float><<<T, 256, 0, stream>>>(x, xn, ln_in_g, ln_in_b);

    // base FFN up: h = gelu(xn @ W1 + b1)
    gemm_bt<0><<<dim3(F / 128, T / 128), 256, 0, stream>>>(
        xn, W1T, b1, h, nullptr, T, F, H, nullptr, 0, nullptr, nullptr, nullptr);

    // adapter 256
    gemm_bt<0><<<dim3(256 / 128, T / 128), 256, 0, stream>>>(
        xn, aw1T0, a256_b1, t0, nullptr, T, 256, H, nullptr, 0, nullptr, nullptr, nullptr);
    gemm_bt<1><<<dim3(H / 128, T / 128), 256, 0, stream>>>(
        t0, aw2T0, a256_b2, adp, nullptr, T, H, 256, widx, 0, nullptr, nullptr, nullptr);

    // adapter 512
    gemm_bt<0><<<dim3(512 / 128, T / 128), 256, 0, stream>>>(
        xn, aw1T1, a512_b1, t1, nullptr, T, 512, H, nullptr, 0, nullptr, nullptr, nullptr);
    gemm_bt<1><<<dim3(H / 128, T / 128), 256, 0, stream>>>(
        t1, aw2T1, a512_b2, adp, nullptr, T, H, 512, widx, 1, nullptr, nullptr, nullptr);

    // h = layernorm(h) in-place (bf16 -> bf16)
    ln_rows<16, unsigned short><<<T, 256, 0, stream>>>(h, h, ln_h_g, ln_h_b);

    // out (fp32) = (h @ W2 + b2) * wm + adaptive * (1 - wm)
    gemm_bt<2><<<dim3(H / 128, T / 128), 256, 0, stream>>>(
        h, W2T, b2, nullptr, out, T, H, F, widx, 0, wm, adp, xn);
}

// Round 3
// 474.261 us; speedup vs baseline: 1.0697x; 1.0697x over previous
//
#include <hip/hip_runtime.h>
#include <cstdint>
#include <cstddef>

typedef unsigned short u16x8 __attribute__((ext_vector_type(8)));
typedef __bf16 bf16x8 __attribute__((ext_vector_type(8)));
typedef float f32x4 __attribute__((ext_vector_type(4)));

__device__ __forceinline__ float b2f(unsigned short u) {
    union { unsigned int i; float f; } v;
    v.i = ((unsigned int)u) << 16;
    return v.f;
}

__device__ __forceinline__ unsigned short f2b(float f) {
    union { float f; unsigned int i; } v;
    v.f = f;
    unsigned int x = v.i;
    unsigned int lsb = (x >> 16) & 1u;
    x += 0x7FFFu + lsb;           // round-to-nearest-even
    return (unsigned short)(x >> 16);
}

__device__ __forceinline__ float gelu_exact(float x) {
    return 0.5f * x * (1.0f + erff(x * 0.70710678118654752f));
}

// async 16B global -> LDS (DMA). lds base is wave-uniform; lane i lands at
// base + i*16 bytes. [m97: global_load_lds_dwordx4]
__device__ __forceinline__ void ld_lds16(const unsigned short* g, unsigned short* l) {
    __builtin_amdgcn_global_load_lds(
        (const __attribute__((address_space(1))) void*)g,
        (__attribute__((address_space(3))) void*)l, 16, 0, 0);
}

// ---------------------------------------------------------------------------
// Transpose + cast: in is R x C row-major fp32, out is C x R row-major bf16.
// ---------------------------------------------------------------------------
__global__ void transpose_f32_bf16(const float* __restrict__ in,
                                   unsigned short* __restrict__ out, int R, int C) {
    __shared__ float tile[32][33];
    int x = blockIdx.x * 32 + threadIdx.x;
    int y0 = blockIdx.y * 32;
    for (int k = 0; k < 32; k += 8)
        tile[threadIdx.y + k][threadIdx.x] = in[(size_t)(y0 + threadIdx.y + k) * C + x];
    __syncthreads();
    int ox = y0 + threadIdx.x;
    int oy = blockIdx.x * 32;
    for (int k = 0; k < 32; k += 8)
        out[(size_t)(oy + threadIdx.y + k) * R + ox] = f2b(tile[threadIdx.x][threadIdx.y + k]);
}

__global__ void concat_bias(const float* __restrict__ b0, const float* __restrict__ b1,
                            float* __restrict__ out) {
    int t = threadIdx.x + blockIdx.x * blockDim.x;
    if (t < 256) out[t] = b0[t];
    else if (t < 768) out[t] = b1[t - 256];
}

// ---------------------------------------------------------------------------
// Row LayerNorm over NPT*256 columns, 256 threads per row. Output bf16.
// ---------------------------------------------------------------------------
__device__ __forceinline__ float ldf(const float* p, int i) { return p[i]; }
__device__ __forceinline__ float ldf(const unsigned short* p, int i) { return b2f(p[i]); }

template <int NPT, typename TIN>
__global__ __launch_bounds__(256) void ln_rows(const TIN* __restrict__ in,
                                               unsigned short* __restrict__ out,
                                               const float* __restrict__ g,
                                               const float* __restrict__ b) {
    const int ncol = NPT * 256;
    const int row = blockIdx.x;
    const int t = threadIdx.x;
    const TIN* xr = in + (size_t)row * ncol;

    float v[NPT];
    float s = 0.f, s2 = 0.f;
#pragma unroll
    for (int i = 0; i < NPT; ++i) {
        float f = ldf(xr, t + (i << 8));
        v[i] = f;
        s += f;
        s2 += f * f;
    }
#pragma unroll
    for (int o = 32; o > 0; o >>= 1) {
        s  += __shfl_down(s, o, 64);
        s2 += __shfl_down(s2, o, 64);
    }
    __shared__ float red[8];
    int lane = t & 63, w = t >> 6;
    if (lane == 0) { red[w] = s; red[4 + w] = s2; }
    __syncthreads();
    if (t == 0) {
        red[0] = red[0] + red[1] + red[2] + red[3];
        red[4] = red[4] + red[5] + red[6] + red[7];
    }
    __syncthreads();
    float inv_n = 1.0f / (float)ncol;
    float mu = red[0] * inv_n;
    float var = red[4] * inv_n - mu * mu;
    float rs = rsqrtf(var + 1e-5f);

    unsigned short* orow = out + (size_t)row * ncol;
#pragma unroll
    for (int i = 0; i < NPT; ++i) {
        int c = t + (i << 8);
        orow[c] = f2b((v[i] - mu) * rs * g[c] + b[c]);
    }
}

// ---------------------------------------------------------------------------
// GEMM: epi(A[M x K] * BT[N x K]^T + bias). A,BT bf16 (row strides lda/ldb);
// fp32 acc. Tile 128x128x32; 256 threads = 4 waves, each 64x64.
// Staging via global_load_lds width-16, unpadded 64B LDS row stride
// (conflict-free for ds_read_b128 fragments).
// EPI: 0 = bias + exact GELU -> bf16 Cb
//      1 = bias -> bf16 Cb only where idx[row] == match
//      2 = bias -> fp32 Cf = val*wm[row] + adaptive_sel*(1-wm[row])
// ---------------------------------------------------------------------------
template <int EPI>
__global__ __launch_bounds__(256) void gemm_bt(
    const unsigned short* __restrict__ A, int lda,
    const unsigned short* __restrict__ BT, int ldb,
    const float* __restrict__ bias, unsigned short* __restrict__ Cb,
    float* __restrict__ Cf, int M, int N, int K,
    const int* __restrict__ idx, int match,
    const float* __restrict__ wm,
    const unsigned short* __restrict__ adaptive,
    const unsigned short* __restrict__ xn) {
    __shared__ __align__(16) unsigned short As[128 * 32];
    __shared__ __align__(16) unsigned short Bs[128 * 32];

    const int t = threadIdx.x;
    const int m0 = blockIdx.y * 128;
    const int n0 = blockIdx.x * 128;

    const int lane = t & 63;
    const int wid = t >> 6;

    // staging: lane i of an instruction covers rel-row i/4, col-chunk (i%4)*8
    const int srow = lane >> 2;
    const int scol = (lane & 3) << 3;

    const int wr = (wid >> 1) << 6;
    const int wc = (wid & 1) << 6;
    const int ml = lane & 15;
    const int q = lane >> 4;

    f32x4 acc[4][4];
#pragma unroll
    for (int i = 0; i < 4; ++i)
#pragma unroll
        for (int j = 0; j < 4; ++j)
#pragma unroll
            for (int r = 0; r < 4; ++r) acc[i][j][r] = 0.0f;

    for (int k0 = 0; k0 < K; k0 += 32) {
#pragma unroll
        for (int hh = 0; hh < 2; ++hh) {
            int rbase = wid * 32 + hh * 16;           // wave-uniform
            int row = rbase + srow;
            ld_lds16(A  + (size_t)(m0 + row) * lda + k0 + scol, &As[rbase * 32]);
            ld_lds16(BT + (size_t)(n0 + row) * ldb + k0 + scol, &Bs[rbase * 32]);
        }
        __syncthreads();

        bf16x8 af[4], bf[4];
#pragma unroll
        for (int i = 0; i < 4; ++i)
            af[i] = *(const bf16x8*)(&As[(wr + i * 16 + ml) * 32 + (q << 3)]);
#pragma unroll
        for (int j = 0; j < 4; ++j)
            bf[j] = *(const bf16x8*)(&Bs[(wc + j * 16 + ml) * 32 + (q << 3)]);
#pragma unroll
        for (int i = 0; i < 4; ++i)
#pragma unroll
            for (int j = 0; j < 4; ++j)
                acc[i][j] = __builtin_amdgcn_mfma_f32_16x16x32_bf16(af[i], bf[j], acc[i][j], 0, 0, 0);
        __syncthreads();
    }

    // C/D layout: col = lane&15, row = quad*4 + reg  [m89/m91-verified]
#pragma unroll
    for (int i = 0; i < 4; ++i) {
#pragma unroll
        for (int j = 0; j < 4; ++j) {
            int col = n0 + wc + j * 16 + ml;
            float bv = bias[col];
#pragma unroll
            for (int r = 0; r < 4; ++r) {
                int row = m0 + wr + i * 16 + q * 4 + r;
                float val = acc[i][j][r] + bv;
                size_t off = (size_t)row * N + col;
                if (EPI == 0) {
                    Cb[off] = f2b(gelu_exact(val));
                } else if (EPI == 1) {
                    if (idx[row] == match) Cb[off] = f2b(val);
                } else {
                    float w = wm[row];
                    int id = idx[row];
                    float a = b2f((id <= 1) ? adaptive[off] : xn[off]);
                    Cf[off] = val * w + a * (1.0f - w);
                }
            }
        }
    }
}

// ---------------------------------------------------------------------------
extern "C" void kernel_launch(void* const* d_in, const int* in_sizes, int n_in,
                              void* d_out, int out_size, void* d_ws, size_t ws_size,
                              hipStream_t stream) {
    const float* x       = (const float*)d_in[0];
    const float* wm      = (const float*)d_in[1];
    const int*   widx    = (const int*)d_in[2];
    const float* ln_in_g = (const float*)d_in[3];
    const float* ln_in_b = (const float*)d_in[4];
    const float* W1      = (const float*)d_in[5];
    const float* b1      = (const float*)d_in[6];
    const float* ln_h_g  = (const float*)d_in[7];
    const float* ln_h_b  = (const float*)d_in[8];
    const float* W2      = (const float*)d_in[9];
    const float* b2      = (const float*)d_in[10];
    const float* a256_w1 = (const float*)d_in[11];
    const float* a256_b1 = (const float*)d_in[12];
    const float* a256_w2 = (const float*)d_in[13];
    const float* a256_b2 = (const float*)d_in[14];
    const float* a512_w1 = (const float*)d_in[15];
    const float* a512_b1 = (const float*)d_in[16];
    const float* a512_w2 = (const float*)d_in[17];
    const float* a512_b2 = (const float*)d_in[18];
    float* out = (float*)d_out;

    const int T = 8192, H = 1024, F = 4096;

    unsigned short* ws0   = (unsigned short*)d_ws;
    unsigned short* xn    = ws0;                       // T*H      bf16
    unsigned short* h     = xn    + (size_t)T * H;     // T*F      bf16
    unsigned short* tt    = h     + (size_t)T * F;     // T*768    bf16 (adapter ups, concat)
    unsigned short* adp   = tt    + (size_t)T * 768;   // T*H      bf16
    unsigned short* W1T   = adp   + (size_t)T * H;     // F*H      bf16
    unsigned short* W2T   = W1T   + (size_t)H * F;     // H*F      bf16
    unsigned short* awup  = W2T   + (size_t)F * H;     // 768*1024 bf16 (a256_w1^T ; a512_w1^T)
    unsigned short* aw2T0 = awup  + (size_t)768 * H;   // 1024*256 bf16
    unsigned short* aw2T1 = aw2T0 + (size_t)H * 256;   // 1024*512 bf16
    float*          ab1   = (float*)(aw2T1 + (size_t)H * 512);  // 768 fp32

    dim3 tb(32, 8);
    transpose_f32_bf16<<<dim3(F / 32,   H / 32), tb, 0, stream>>>(W1, W1T, H, F);
    transpose_f32_bf16<<<dim3(H / 32,   F / 32), tb, 0, stream>>>(W2, W2T, F, H);
    transpose_f32_bf16<<<dim3(256 / 32, H / 32), tb, 0, stream>>>(a256_w1, awup, H, 256);
    transpose_f32_bf16<<<dim3(512 / 32, H / 32), tb, 0, stream>>>(a512_w1, awup + (size_t)256 * H, H, 512);
    transpose_f32_bf16<<<dim3(H / 32, 256 / 32), tb, 0, stream>>>(a256_w2, aw2T0, 256, H);
    transpose_f32_bf16<<<dim3(H / 32, 512 / 32), tb, 0, stream>>>(a512_w2, aw2T1, 512, H);
    concat_bias<<<3, 256, 0, stream>>>(a256_b1, a512_b1, ab1);

    // x (fp32) -> x_norm (bf16)
    ln_rows<4, float><<<T, 256, 0, stream>>>(x, xn, ln_in_g, ln_in_b);

    // base FFN up: h = gelu(xn @ W1 + b1)
    gemm_bt<0><<<dim3(F / 128, T / 128), 256, 0, stream>>>(
        xn, H, W1T, H, b1, h, nullptr, T, F, H, nullptr, 0, nullptr, nullptr, nullptr);

    // merged adapter ups: tt = gelu(xn @ [a256_w1 | a512_w1] + [b1|b1])
    gemm_bt<0><<<dim3(768 / 128, T / 128), 256, 0, stream>>>(
        xn, H, awup, H, ab1, tt, nullptr, T, 768, H, nullptr, 0, nullptr, nullptr, nullptr);

    // adapter downs (routed rows only)
    gemm_bt<1><<<dim3(H / 128, T / 128), 256, 0, stream>>>(
        tt, 768, aw2T0, 256, a256_b2, adp, nullptr, T, H, 256, widx, 0, nullptr, nullptr, nullptr);
    gemm_bt<1><<<dim3(H / 128, T / 128), 256, 0, stream>>>(
        tt + 256, 768, aw2T1, 512, a512_b2, adp, nullptr, T, H, 512, widx, 1, nullptr, nullptr, nullptr);

    // h = layernorm(h) in-place (bf16 -> bf16)
    ln_rows<16, unsigned short><<<T, 256, 0, stream>>>(h, h, ln_h_g, ln_h_b);

    // out (fp32) = (h @ W2 + b2) * wm + adaptive * (1 - wm)
    gemm_bt<2><<<dim3(H / 128, T / 128), 256, 0, stream>>>(
        h, F, W2T, F, b2, nullptr, out, T, H, F, widx, 0, wm, adp, xn);
}

// Round 4
// 453.254 us; speedup vs baseline: 1.1193x; 1.0463x over previous
//
#include <hip/hip_runtime.h>
#include <cstdint>
#include <cstddef>

typedef unsigned short u16x8 __attribute__((ext_vector_type(8)));
typedef __bf16 bf16x8 __attribute__((ext_vector_type(8)));
typedef float f32x4 __attribute__((ext_vector_type(4)));

__device__ __forceinline__ float b2f(unsigned short u) {
    union { unsigned int i; float f; } v;
    v.i = ((unsigned int)u) << 16;
    return v.f;
}

__device__ __forceinline__ unsigned short f2b(float f) {
    union { float f; unsigned int i; } v;
    v.f = f;
    unsigned int x = v.i;
    unsigned int lsb = (x >> 16) & 1u;
    x += 0x7FFFu + lsb;           // round-to-nearest-even
    return (unsigned short)(x >> 16);
}

__device__ __forceinline__ float gelu_exact(float x) {
    return 0.5f * x * (1.0f + erff(x * 0.70710678118654752f));
}

// async 16B global -> LDS (DMA). lds base is wave-uniform; lane i lands at
// base + i*16 bytes. [m97: global_load_lds_dwordx4]
__device__ __forceinline__ void ld_lds16(const unsigned short* g, unsigned short* l) {
    __builtin_amdgcn_global_load_lds(
        (const __attribute__((address_space(1))) void*)g,
        (__attribute__((address_space(3))) void*)l, 16, 0, 0);
}

// ---------------------------------------------------------------------------
// Transpose + cast: in is R x C row-major fp32, out is C x R row-major bf16.
// ---------------------------------------------------------------------------
__global__ void transpose_f32_bf16(const float* __restrict__ in,
                                   unsigned short* __restrict__ out, int R, int C) {
    __shared__ float tile[32][33];
    int x = blockIdx.x * 32 + threadIdx.x;
    int y0 = blockIdx.y * 32;
    for (int k = 0; k < 32; k += 8)
        tile[threadIdx.y + k][threadIdx.x] = in[(size_t)(y0 + threadIdx.y + k) * C + x];
    __syncthreads();
    int ox = y0 + threadIdx.x;
    int oy = blockIdx.x * 32;
    for (int k = 0; k < 32; k += 8)
        out[(size_t)(oy + threadIdx.y + k) * R + ox] = f2b(tile[threadIdx.x][threadIdx.y + k]);
}

__global__ void concat_bias(const float* __restrict__ b0, const float* __restrict__ b1,
                            float* __restrict__ out) {
    int t = threadIdx.x + blockIdx.x * blockDim.x;
    if (t < 256) out[t] = b0[t];
    else if (t < 768) out[t] = b1[t - 256];
}

// ---------------------------------------------------------------------------
// Row LayerNorm over NPT*256 columns, 256 threads per row. Output bf16.
// ---------------------------------------------------------------------------
__device__ __forceinline__ float ldf(const float* p, int i) { return p[i]; }
__device__ __forceinline__ float ldf(const unsigned short* p, int i) { return b2f(p[i]); }

template <int NPT, typename TIN>
__global__ __launch_bounds__(256) void ln_rows(const TIN* __restrict__ in,
                                               unsigned short* __restrict__ out,
                                               const float* __restrict__ g,
                                               const float* __restrict__ b) {
    const int ncol = NPT * 256;
    const int row = blockIdx.x;
    const int t = threadIdx.x;
    const TIN* xr = in + (size_t)row * ncol;

    float v[NPT];
    float s = 0.f, s2 = 0.f;
#pragma unroll
    for (int i = 0; i < NPT; ++i) {
        float f = ldf(xr, t + (i << 8));
        v[i] = f;
        s += f;
        s2 += f * f;
    }
#pragma unroll
    for (int o = 32; o > 0; o >>= 1) {
        s  += __shfl_down(s, o, 64);
        s2 += __shfl_down(s2, o, 64);
    }
    __shared__ float red[8];
    int lane = t & 63, w = t >> 6;
    if (lane == 0) { red[w] = s; red[4 + w] = s2; }
    __syncthreads();
    if (t == 0) {
        red[0] = red[0] + red[1] + red[2] + red[3];
        red[4] = red[4] + red[5] + red[6] + red[7];
    }
    __syncthreads();
    float inv_n = 1.0f / (float)ncol;
    float mu = red[0] * inv_n;
    float var = red[4] * inv_n - mu * mu;
    float rs = rsqrtf(var + 1e-5f);

    unsigned short* orow = out + (size_t)row * ncol;
#pragma unroll
    for (int i = 0; i < NPT; ++i) {
        int c = t + (i << 8);
        orow[c] = f2b((v[i] - mu) * rs * g[c] + b[c]);
    }
}

// ---------------------------------------------------------------------------
// GEMM: epi(A[M x K] * BT[N x K]^T + bias). A,BT bf16 (row strides lda/ldb);
// fp32 acc. Tile 128x128x32; 256 threads = 4 waves, each 64x64.
// Double-buffered LDS + single barrier per iter: DMA(k+1) issued before
// compute(k); its vmcnt drain lands at the NEXT iteration's barrier, so the
// global->LDS latency is covered by a full compute phase.
// XOR swizzle: LDS row r holds column-chunk (c ^ (r&3)); readers use
// chunk q ^ (ml&3) -> worst-case 2-way bank aliasing (free).
// EPI: 0 = bias + exact GELU -> bf16 Cb
//      1 = bias -> bf16 Cb only where idx[row] == match
//      2 = bias -> fp32 Cf = val*wm[row] + adaptive_sel*(1-wm[row])
// ---------------------------------------------------------------------------
template <int EPI>
__global__ __launch_bounds__(256) void gemm_bt(
    const unsigned short* __restrict__ A, int lda,
    const unsigned short* __restrict__ BT, int ldb,
    const float* __restrict__ bias, unsigned short* __restrict__ Cb,
    float* __restrict__ Cf, int M, int N, int K,
    const int* __restrict__ idx, int match,
    const float* __restrict__ wm,
    const unsigned short* __restrict__ adaptive,
    const unsigned short* __restrict__ xn) {
    __shared__ __align__(16) unsigned short As[2][128 * 32];
    __shared__ __align__(16) unsigned short Bs[2][128 * 32];

    const int t = threadIdx.x;
    const int m0 = blockIdx.y * 128;
    const int n0 = blockIdx.x * 128;

    const int lane = t & 63;
    const int wid = t >> 6;

    // staging: lane i covers LDS rel-row i/4, chunk i%4; source column-chunk
    // is XOR-swizzled by row so readers land conflict-light.
    const int srow = lane >> 2;
    const int sch  = (lane & 3) ^ (srow & 3);   // source chunk (global col/8)
    const int scol = sch << 3;

    const int wr = (wid >> 1) << 6;
    const int wc = (wid & 1) << 6;
    const int ml = lane & 15;
    const int q = lane >> 4;
    const int qsw = ((q ^ (ml & 3)) << 3);      // swizzled LDS element offset

    f32x4 acc[4][4];
#pragma unroll
    for (int i = 0; i < 4; ++i)
#pragma unroll
        for (int j = 0; j < 4; ++j)
#pragma unroll
            for (int r = 0; r < 4; ++r) acc[i][j][r] = 0.0f;

    const int nk = K >> 5;

#define STAGE(KT, BUF)                                                          \
    {                                                                           \
        _Pragma("unroll")                                                       \
        for (int hh = 0; hh < 2; ++hh) {                                        \
            int rbase = wid * 32 + hh * 16;                                     \
            int row = rbase + srow;                                             \
            ld_lds16(A  + (size_t)(m0 + row) * lda + (KT) * 32 + scol,          \
                     &As[BUF][rbase * 32]);                                     \
            ld_lds16(BT + (size_t)(n0 + row) * ldb + (KT) * 32 + scol,          \
                     &Bs[BUF][rbase * 32]);                                     \
        }                                                                       \
    }

    STAGE(0, 0);
    for (int kt = 0; kt < nk; ++kt) {
        const int cur = kt & 1;
        __syncthreads();                 // drains DMA(kt) (in flight since kt-1)
        if (kt + 1 < nk) STAGE(kt + 1, cur ^ 1);

        bf16x8 af[4], bf[4];
#pragma unroll
        for (int i = 0; i < 4; ++i)
            af[i] = *(const bf16x8*)(&As[cur][(wr + i * 16 + ml) * 32 + qsw]);
#pragma unroll
        for (int j = 0; j < 4; ++j)
            bf[j] = *(const bf16x8*)(&Bs[cur][(wc + j * 16 + ml) * 32 + qsw]);
#pragma unroll
        for (int i = 0; i < 4; ++i)
#pragma unroll
            for (int j = 0; j < 4; ++j)
                acc[i][j] = __builtin_amdgcn_mfma_f32_16x16x32_bf16(af[i], bf[j], acc[i][j], 0, 0, 0);
    }
#undef STAGE

    // C/D layout: col = lane&15, row = quad*4 + reg  [m89/m91-verified]
#pragma unroll
    for (int i = 0; i < 4; ++i) {
#pragma unroll
        for (int j = 0; j < 4; ++j) {
            int col = n0 + wc + j * 16 + ml;
            float bv = bias[col];
#pragma unroll
            for (int r = 0; r < 4; ++r) {
                int row = m0 + wr + i * 16 + q * 4 + r;
                float val = acc[i][j][r] + bv;
                size_t off = (size_t)row * N + col;
                if (EPI == 0) {
                    Cb[off] = f2b(gelu_exact(val));
                } else if (EPI == 1) {
                    if (idx[row] == match) Cb[off] = f2b(val);
                } else {
                    float w = wm[row];
                    int id = idx[row];
                    float a = b2f((id <= 1) ? adaptive[off] : xn[off]);
                    Cf[off] = val * w + a * (1.0f - w);
                }
            }
        }
    }
}

// ---------------------------------------------------------------------------
extern "C" void kernel_launch(void* const* d_in, const int* in_sizes, int n_in,
                              void* d_out, int out_size, void* d_ws, size_t ws_size,
                              hipStream_t stream) {
    const float* x       = (const float*)d_in[0];
    const float* wm      = (const float*)d_in[1];
    const int*   widx    = (const int*)d_in[2];
    const float* ln_in_g = (const float*)d_in[3];
    const float* ln_in_b = (const float*)d_in[4];
    const float* W1      = (const float*)d_in[5];
    const float* b1      = (const float*)d_in[6];
    const float* ln_h_g  = (const float*)d_in[7];
    const float* ln_h_b  = (const float*)d_in[8];
    const float* W2      = (const float*)d_in[9];
    const float* b2      = (const float*)d_in[10];
    const float* a256_w1 = (const float*)d_in[11];
    const float* a256_b1 = (const float*)d_in[12];
    const float* a256_w2 = (const float*)d_in[13];
    const float* a256_b2 = (const float*)d_in[14];
    const float* a512_w1 = (const float*)d_in[15];
    const float* a512_b1 = (const float*)d_in[16];
    const float* a512_w2 = (const float*)d_in[17];
    const float* a512_b2 = (const float*)d_in[18];
    float* out = (float*)d_out;

    const int T = 8192, H = 1024, F = 4096;

    unsigned short* ws0   = (unsigned short*)d_ws;
    unsigned short* xn    = ws0;                       // T*H      bf16
    unsigned short* h     = xn    + (size_t)T * H;     // T*F      bf16
    unsigned short* tt    = h     + (size_t)T * F;     // T*768    bf16 (adapter ups, concat)
    unsigned short* adp   = tt    + (size_t)T * 768;   // T*H      bf16
    unsigned short* W1T   = adp   + (size_t)T * H;     // F*H      bf16
    unsigned short* W2T   = W1T   + (size_t)H * F;     // H*F      bf16
    unsigned short* awup  = W2T   + (size_t)F * H;     // 768*1024 bf16 (a256_w1^T ; a512_w1^T)
    unsigned short* aw2T0 = awup  + (size_t)768 * H;   // 1024*256 bf16
    unsigned short* aw2T1 = aw2T0 + (size_t)H * 256;   // 1024*512 bf16
    float*          ab1   = (float*)(aw2T1 + (size_t)H * 512);  // 768 fp32

    dim3 tb(32, 8);
    transpose_f32_bf16<<<dim3(F / 32,   H / 32), tb, 0, stream>>>(W1, W1T, H, F);
    transpose_f32_bf16<<<dim3(H / 32,   F / 32), tb, 0, stream>>>(W2, W2T, F, H);
    transpose_f32_bf16<<<dim3(256 / 32, H / 32), tb, 0, stream>>>(a256_w1, awup, H, 256);
    transpose_f32_bf16<<<dim3(512 / 32, H / 32), tb, 0, stream>>>(a512_w1, awup + (size_t)256 * H, H, 512);
    transpose_f32_bf16<<<dim3(H / 32, 256 / 32), tb, 0, stream>>>(a256_w2, aw2T0, 256, H);
    transpose_f32_bf16<<<dim3(H / 32, 512 / 32), tb, 0, stream>>>(a512_w2, aw2T1, 512, H);
    concat_bias<<<3, 256, 0, stream>>>(a256_b1, a512_b1, ab1);

    // x (fp32) -> x_norm (bf16)
    ln_rows<4, float><<<T, 256, 0, stream>>>(x, xn, ln_in_g, ln_in_b);

    // base FFN up: h = gelu(xn @ W1 + b1)
    gemm_bt<0><<<dim3(F / 128, T / 128), 256, 0, stream>>>(
        xn, H, W1T, H, b1, h, nullptr, T, F, H, nullptr, 0, nullptr, nullptr, nullptr);

    // merged adapter ups: tt = gelu(xn @ [a256_w1 | a512_w1] + [b1|b1])
    gemm_bt<0><<<dim3(768 / 128, T / 128), 256, 0, stream>>>(
        xn, H, awup, H, ab1, tt, nullptr, T, 768, H, nullptr, 0, nullptr, nullptr, nullptr);

    // adapter downs (routed rows only)
    gemm_bt<1><<<dim3(H / 128, T / 128), 256, 0, stream>>>(
        tt, 768, aw2T0, 256, a256_b2, adp, nullptr, T, H, 256, widx, 0, nullptr, nullptr, nullptr);
    gemm_bt<1><<<dim3(H / 128, T / 128), 256, 0, stream>>>(
        tt + 256, 768, aw2T1, 512, a512_b2, adp, nullptr, T, H, 512, widx, 1, nullptr, nullptr, nullptr);

    // h = layernorm(h) in-place (bf16 -> bf16)
    ln_rows<16, unsigned short><<<T, 256, 0, stream>>>(h, h, ln_h_g, ln_h_b);

    // out (fp32) = (h @ W2 + b2) * wm + adaptive * (1 - wm)
    gemm_bt<2><<<dim3(H / 128, T / 128), 256, 0, stream>>>(
        h, F, W2T, F, b2, nullptr, out, T, H, F, widx, 0, wm, adp, xn);
}